// Round 3
// baseline (405.054 us; speedup 1.0000x reference)
//
#include <hip/hip_runtime.h>
#include <hip/hip_bf16.h>

#define C_DIM 256
#define L_DIM 4096
#define H_DIM 512
#define KW    31
#define PADW  15

typedef unsigned short u16;
typedef unsigned int   u32;
typedef short bf16x8 __attribute__((ext_vector_type(8)));
typedef float f32x4  __attribute__((ext_vector_type(4)));

__device__ __forceinline__ u16 f2bf(float f) {
    u32 u = __float_as_uint(f);
    u32 r = (u + 0x7FFFu + ((u >> 16) & 1u)) >> 16;
    return (u16)r;
}
__device__ __forceinline__ float bf2f(u16 h) {
    return __uint_as_float(((u32)h) << 16);
}

typedef __attribute__((address_space(1))) const unsigned int gq_t;
typedef __attribute__((address_space(3))) unsigned int lq_t;
__device__ __forceinline__ void async16(void* lds, const void* g) {
    __builtin_amdgcn_global_load_lds((gq_t*)g, (lq_t*)lds, 16, 0, 0);
}

// ---------------------------------------------------------------------------
// prep: fold BN0 into expand weights (bf16), compute per-channel affines.
// ---------------------------------------------------------------------------
__global__ __launch_bounds__(256) void prep_kernel(
    const float* __restrict__ w_expand,
    const float* __restrict__ g0, const float* __restrict__ b0,
    const float* __restrict__ m0, const float* __restrict__ v0,
    const float* __restrict__ g1, const float* __restrict__ b1,
    const float* __restrict__ m1, const float* __restrict__ v1,
    const float* __restrict__ g2, const float* __restrict__ b2,
    const float* __restrict__ m2, const float* __restrict__ v2,
    const float* __restrict__ g3, const float* __restrict__ b3,
    const float* __restrict__ m3, const float* __restrict__ v3,
    u16* __restrict__ W0bf, float* __restrict__ A1, float* __restrict__ B1,
    float* __restrict__ A2, float* __restrict__ B2,
    float* __restrict__ A3, float* __restrict__ B3)
{
    __shared__ float red[256];
    const int h = blockIdx.x;
    const int c = threadIdx.x;

    float inv0 = g0[c] / sqrtf(v0[c] + 1e-5f);
    float add0 = b0[c] - m0[c] * inv0;
    float w = w_expand[h * C_DIM + c];
    W0bf[h * C_DIM + c] = f2bf(w * inv0);
    red[c] = add0 * w;
    __syncthreads();
    for (int s = 128; s > 0; s >>= 1) {
        if (c < s) red[c] += red[c + s];
        __syncthreads();
    }
    if (c == 0) {
        float bias0 = red[0];
        float inv1 = g1[h] / sqrtf(v1[h] + 1e-5f);
        A1[h] = inv1;
        B1[h] = bias0 * inv1 + (b1[h] - m1[h] * inv1);
        float inv2 = g2[h] / sqrtf(v2[h] + 1e-5f);
        A2[h] = inv2;
        B2[h] = b2[h] - m2[h] * inv2;
        if (h < C_DIM) {
            float inv3 = g3[h] / sqrtf(v3[h] + 1e-5f);
            A3[h] = inv3;
            B3[h] = b3[h] - m3[h] * inv3;
        }
    }
}

__global__ __launch_bounds__(256) void convw_kernel(
    const float* __restrict__ w, u16* __restrict__ o, int n)
{
    int i = blockIdx.x * 256 + threadIdx.x;
    if (i < n) o[i] = f2bf(w[i]);
}

// ---------------------------------------------------------------------------
// convx: x fp32 [C][L] -> xT bf16 [L][C]  (per batch, LDS tile transpose)
// ---------------------------------------------------------------------------
__global__ __launch_bounds__(256) void convx_kernel(
    const float* __restrict__ x, u16* __restrict__ xT)
{
    __shared__ u16 t_s[64][68];
    const int b = blockIdx.z, c0 = blockIdx.y * 64, l0 = blockIdx.x * 64;
    const int tid = threadIdx.x;
    const float* xb = x + (size_t)b * C_DIM * L_DIM;
    {
        const int cl = tid >> 2, lg = (tid & 3) * 16;
        const float* src = xb + (size_t)(c0 + cl) * L_DIM + l0 + lg;
#pragma unroll
        for (int j = 0; j < 16; j += 4) {
            float4 v = *(const float4*)(src + j);
            ushort4 o;
            o.x = f2bf(v.x); o.y = f2bf(v.y); o.z = f2bf(v.z); o.w = f2bf(v.w);
            *(ushort4*)&t_s[cl][lg + j] = o;
        }
    }
    __syncthreads();
    {
        const int ll = tid >> 2, cg = (tid & 3) * 16;
        u32 w0[4], w1[4];
#pragma unroll
        for (int j = 0; j < 4; ++j) {
            w0[j] = (u32)t_s[cg + 2*j][ll] | ((u32)t_s[cg + 2*j + 1][ll] << 16);
            w1[j] = (u32)t_s[cg + 8 + 2*j][ll] | ((u32)t_s[cg + 9 + 2*j][ll] << 16);
        }
        u16* dst = xT + ((size_t)b * L_DIM + l0 + ll) * C_DIM + c0 + cg;
        uint4 o0; o0.x = w0[0]; o0.y = w0[1]; o0.z = w0[2]; o0.w = w0[3];
        uint4 o1; o1.x = w1[0]; o1.y = w1[1]; o1.z = w1[2]; o1.w = w1[3];
        *(uint4*)(dst)     = o0;
        *(uint4*)(dst + 8) = o1;
    }
}

// ---------------------------------------------------------------------------
// gemm_bt: D = A[M][K] * BT[N][K]^T, bf16 MFMA 16x16x32, 128x128 tile, BK=64
// EPI 0: Out = bf16 h1, v = relu(acc*Sa[row] + Sb[row])
// EPI 1: Out = fp32 out, v = acc*Sa[row] + Sb[row] + Xs[row][col]
// ---------------------------------------------------------------------------
template<int KDIM, int EPI>
__global__ __launch_bounds__(256) void gemm_bt_kernel(
    const u16* __restrict__ A,    // [M][KDIM] bf16
    const u16* __restrict__ BT,   // per b: [L_DIM][KDIM] bf16
    void* __restrict__ Out,
    const float* __restrict__ Sa, const float* __restrict__ Sb,
    const float* __restrict__ Xs)
{
    __shared__ short Asm[128 * 64];
    __shared__ short Bsm[128 * 64];
    const int b = blockIdx.z;
    const int bm = blockIdx.y * 128;
    const int bn = blockIdx.x * 128;
    const int tid = threadIdx.x;
    const int wave = tid >> 6, lane = tid & 63;
    const int wr = wave >> 1, wc = wave & 1;
    const int l15 = lane & 15, kg = lane >> 4;

    const u16* Bb = BT + (size_t)b * L_DIM * KDIM;

    const int srow = wave * 32 + (lane >> 3);
    const int scol = (lane & 7) * 8;
    const u16* gA = A  + (size_t)(bm + srow) * KDIM + scol;
    const u16* gB = Bb + (size_t)(bn + srow) * KDIM + scol;
    short* lA = Asm + wave * 32 * 64;
    short* lB = Bsm + wave * 32 * 64;

    f32x4 acc[4][4] = {};

    for (int kt = 0; kt < KDIM / 64; ++kt) {
        __syncthreads();
#pragma unroll
        for (int j = 0; j < 4; ++j) {
            async16(lA + j * 8 * 64, gA + (size_t)j * 8 * KDIM);
            async16(lB + j * 8 * 64, gB + (size_t)j * 8 * KDIM);
        }
        gA += 64; gB += 64;
        __syncthreads();
#pragma unroll
        for (int ks = 0; ks < 2; ++ks) {
            bf16x8 af[4], bf[4];
#pragma unroll
            for (int m = 0; m < 4; ++m)
                af[m] = *(const bf16x8*)&Asm[(wr * 64 + m * 16 + l15) * 64 + ks * 32 + kg * 8];
#pragma unroll
            for (int n = 0; n < 4; ++n)
                bf[n] = *(const bf16x8*)&Bsm[(wc * 64 + n * 16 + l15) * 64 + ks * 32 + kg * 8];
#pragma unroll
            for (int m = 0; m < 4; ++m)
#pragma unroll
                for (int n = 0; n < 4; ++n)
                    acc[m][n] = __builtin_amdgcn_mfma_f32_16x16x32_bf16(
                        af[m], bf[n], acc[m][n], 0, 0, 0);
        }
    }

    const int orow0 = bm + wr * 64;
    const int ocol = bn + wc * 64 + l15;
    if constexpr (EPI == 0) {
        u16* O = (u16*)Out + (size_t)b * H_DIM * L_DIM;
#pragma unroll
        for (int m = 0; m < 4; ++m)
#pragma unroll
        for (int r = 0; r < 4; ++r) {
            const int row = orow0 + m * 16 + kg * 4 + r;
            const float s = Sa[row], t = Sb[row];
#pragma unroll
            for (int n = 0; n < 4; ++n) {
                float v = acc[m][n][r] * s + t;
                v = v > 0.f ? v : 0.f;
                O[(size_t)row * L_DIM + ocol + n * 16] = f2bf(v);
            }
        }
    } else {
        float* O = (float*)Out + (size_t)b * C_DIM * L_DIM;
        const float* X = Xs + (size_t)b * C_DIM * L_DIM;
#pragma unroll
        for (int m = 0; m < 4; ++m)
#pragma unroll
        for (int r = 0; r < 4; ++r) {
            const int row = orow0 + m * 16 + kg * 4 + r;
            const float s = Sa[row], t = Sb[row];
#pragma unroll
            for (int n = 0; n < 4; ++n) {
                float v = acc[m][n][r] * s + t + X[(size_t)row * L_DIM + ocol + n * 16];
                O[(size_t)row * L_DIM + ocol + n * 16] = v;
            }
        }
    }
}

// ---------------------------------------------------------------------------
// dw: depthwise conv K=31 on h1 [H][L] bf16 -> h2T [L][H] bf16, BN2+ReLU.
// Tile: 32 h x 128 l. LDS ~24.8 KB -> 6 blocks/CU. Conflict-free layouts:
//   in_s stride 162 u16 (bank stride 17), wt_s [32][33] (bank (hl+u)%32),
//   out_s [128][40].
// Two 8-output passes keep VGPR low (win[40] + acc[8]).
// ---------------------------------------------------------------------------
__global__ __launch_bounds__(256) void dw_kernel(
    const u16* __restrict__ h1, const float* __restrict__ w_dw,
    u16* __restrict__ h2T,
    const float* __restrict__ A2, const float* __restrict__ B2)
{
    __shared__ u16   in_s[32][162];   // origin l0-16, cols 0..159 used
    __shared__ float wt_s[32][33];
    __shared__ u16   out_s[128][40];
    const int b = blockIdx.z, h0 = blockIdx.y * 32, l0 = blockIdx.x * 128;
    const int tid = threadIdx.x;
    const u16* hb = h1 + (size_t)b * H_DIM * L_DIM;

    for (int idx = tid; idx < 32 * 31; idx += 256)
        wt_s[idx / 31][idx % 31] = w_dw[(h0 + idx / 31) * 31 + idx % 31];

    // load 32 rows x 160 cols (l = l0-16 .. l0+143), 8 bf16 per unit
    for (int idx = tid; idx < 32 * 20; idx += 256) {
        const int r = idx / 20, g = idx % 20;
        const int bl = l0 - 16 + g * 8;
        const u16* src = hb + (size_t)(h0 + r) * L_DIM + bl;
        u16 t0, t1, t2, t3, t4, t5, t6, t7;
        if (bl >= 0 && bl + 8 <= L_DIM) {
            ushort4 a = *(const ushort4*)(src);
            ushort4 c = *(const ushort4*)(src + 4);
            t0 = a.x; t1 = a.y; t2 = a.z; t3 = a.w;
            t4 = c.x; t5 = c.y; t6 = c.z; t7 = c.w;
        } else {
            t0 = (bl + 0 >= 0 && bl + 0 < L_DIM) ? src[0] : (u16)0;
            t1 = (bl + 1 >= 0 && bl + 1 < L_DIM) ? src[1] : (u16)0;
            t2 = (bl + 2 >= 0 && bl + 2 < L_DIM) ? src[2] : (u16)0;
            t3 = (bl + 3 >= 0 && bl + 3 < L_DIM) ? src[3] : (u16)0;
            t4 = (bl + 4 >= 0 && bl + 4 < L_DIM) ? src[4] : (u16)0;
            t5 = (bl + 5 >= 0 && bl + 5 < L_DIM) ? src[5] : (u16)0;
            t6 = (bl + 6 >= 0 && bl + 6 < L_DIM) ? src[6] : (u16)0;
            t7 = (bl + 7 >= 0 && bl + 7 < L_DIM) ? src[7] : (u16)0;
        }
        ushort2 p;
        p.x = t0; p.y = t1; *(ushort2*)&in_s[r][g * 8 + 0] = p;
        p.x = t2; p.y = t3; *(ushort2*)&in_s[r][g * 8 + 2] = p;
        p.x = t4; p.y = t5; *(ushort2*)&in_s[r][g * 8 + 4] = p;
        p.x = t6; p.y = t7; *(ushort2*)&in_s[r][g * 8 + 6] = p;
    }
    __syncthreads();

    const int hl = tid & 31, lg = tid >> 5;   // 8 l-groups of 16
    const int h = h0 + hl;
    const float s2 = A2[h], t2v = B2[h];

#pragma unroll
    for (int p = 0; p < 2; ++p) {
        const int base = lg * 16 + p * 8;     // output l-offset base
        float win[40];
#pragma unroll
        for (int j = 0; j < 40; j += 2) {
            ushort2 u2 = *(const ushort2*)&in_s[hl][base + j];
            win[j]     = bf2f(u2.x);
            win[j + 1] = bf2f(u2.y);
        }
        float acc[8] = {};
#pragma unroll
        for (int u = 0; u < KW; ++u) {
            const float wv = wt_s[hl][u];
#pragma unroll
            for (int i = 0; i < 8; ++i) acc[i] += win[i + 1 + u] * wv;
        }
#pragma unroll
        for (int i = 0; i < 8; ++i) {
            float v = acc[i] * s2 + t2v;
            out_s[base + i][hl] = f2bf(v > 0.f ? v : 0.f);
        }
    }
    __syncthreads();

    // coalesced transposed write: 128 rows x 64B, 2 threads per row
    const int row = tid >> 1, half = (tid & 1) * 16;
    u16* dst = h2T + ((size_t)b * L_DIM + l0 + row) * H_DIM + h0 + half;
    uint4 a0 = *(const uint4*)&out_s[row][half];
    uint4 a1 = *(const uint4*)&out_s[row][half + 8];
    ((uint4*)dst)[0] = a0;
    ((uint4*)dst)[1] = a1;
}

extern "C" void kernel_launch(void* const* d_in, const int* in_sizes, int n_in,
                              void* d_out, int out_size, void* d_ws, size_t ws_size,
                              hipStream_t stream) {
    const float* x        = (const float*)d_in[0];
    const float* w_expand = (const float*)d_in[1];
    const float* w_dw     = (const float*)d_in[2];
    const float* w_proj   = (const float*)d_in[3];
    const float* g0 = (const float*)d_in[4],  *b0 = (const float*)d_in[5];
    const float* m0 = (const float*)d_in[6],  *v0 = (const float*)d_in[7];
    const float* g1 = (const float*)d_in[8],  *b1 = (const float*)d_in[9];
    const float* m1 = (const float*)d_in[10], *v1 = (const float*)d_in[11];
    const float* g2 = (const float*)d_in[12], *b2 = (const float*)d_in[13];
    const float* m2 = (const float*)d_in[14], *v2 = (const float*)d_in[15];
    const float* g3 = (const float*)d_in[16], *b3 = (const float*)d_in[17];
    const float* m3 = (const float*)d_in[18], *v3 = (const float*)d_in[19];
    float* out = (float*)d_out;

    const int B = in_sizes[0] / (C_DIM * L_DIM);

    char* base = (char*)d_ws;
    size_t off = 0;
    u16* W0bf = (u16*)(base + off); off += (size_t)H_DIM * C_DIM * 2;
    u16* Wpbf = (u16*)(base + off); off += (size_t)C_DIM * H_DIM * 2;
    float* A1p = (float*)(base + off); off += H_DIM * 4;
    float* B1p = (float*)(base + off); off += H_DIM * 4;
    float* A2p = (float*)(base + off); off += H_DIM * 4;
    float* B2p = (float*)(base + off); off += H_DIM * 4;
    float* A3p = (float*)(base + off); off += C_DIM * 4;
    float* B3p = (float*)(base + off); off += C_DIM * 4;
    off = (off + 255) & ~(size_t)255;

    const size_t per_b = ((size_t)L_DIM * C_DIM + 2 * (size_t)H_DIM * L_DIM) * 2;
    int nb = 1;
    const int cands[6] = {32, 16, 8, 4, 2, 1};
    for (int i = 0; i < 6; ++i) {
        if (B % cands[i]) continue;
        if (off + per_b * cands[i] <= ws_size) { nb = cands[i]; break; }
    }
    u16* xT  = (u16*)(base + off);
    u16* h1  = xT + (size_t)nb * L_DIM * C_DIM;
    u16* h2T = h1 + (size_t)nb * H_DIM * L_DIM;

    prep_kernel<<<H_DIM, 256, 0, stream>>>(
        w_expand, g0, b0, m0, v0, g1, b1, m1, v1, g2, b2, m2, v2,
        g3, b3, m3, v3, W0bf, A1p, B1p, A2p, B2p, A3p, B3p);
    convw_kernel<<<(C_DIM * H_DIM + 255) / 256, 256, 0, stream>>>(
        w_proj, Wpbf, C_DIM * H_DIM);

    for (int cs = 0; cs < B; cs += nb) {
        const float* xb = x + (size_t)cs * C_DIM * L_DIM;
        float* ob = out + (size_t)cs * C_DIM * L_DIM;
        convx_kernel<<<dim3(L_DIM / 64, C_DIM / 64, nb), 256, 0, stream>>>(xb, xT);
        gemm_bt_kernel<C_DIM, 0><<<dim3(L_DIM / 128, H_DIM / 128, nb), 256, 0, stream>>>(
            W0bf, xT, h1, A1p, B1p, nullptr);
        dw_kernel<<<dim3(L_DIM / 128, H_DIM / 32, nb), 256, 0, stream>>>(
            h1, w_dw, h2T, A2p, B2p);
        gemm_bt_kernel<H_DIM, 1><<<dim3(L_DIM / 128, C_DIM / 128, nb), 256, 0, stream>>>(
            Wpbf, h2T, ob, A3p, B3p, xb);
    }
}

// Round 4
// 301.945 us; speedup vs baseline: 1.3415x; 1.3415x over previous
//
#include <hip/hip_runtime.h>
#include <hip/hip_bf16.h>

#define C_DIM 256
#define L_DIM 4096
#define H_DIM 512
#define KW    31
#define PADW  15

typedef unsigned short u16;
typedef unsigned int   u32;
typedef short bf16x8 __attribute__((ext_vector_type(8)));
typedef float f32x4  __attribute__((ext_vector_type(4)));

__device__ __forceinline__ u16 f2bf(float f) {
    u32 u = __float_as_uint(f);
    u32 r = (u + 0x7FFFu + ((u >> 16) & 1u)) >> 16;
    return (u16)r;
}
__device__ __forceinline__ float bf2f(u16 h) {
    return __uint_as_float(((u32)h) << 16);
}

typedef __attribute__((address_space(1))) const unsigned int gq_t;
typedef __attribute__((address_space(3))) unsigned int lq_t;
__device__ __forceinline__ void async16(void* lds, const void* g) {
    __builtin_amdgcn_global_load_lds((gq_t*)g, (lq_t*)lds, 16, 0, 0);
}

// ---------------------------------------------------------------------------
// prep: fold BN0 into expand weights (bf16), compute per-channel affines.
// ---------------------------------------------------------------------------
__global__ __launch_bounds__(256) void prep_kernel(
    const float* __restrict__ w_expand,
    const float* __restrict__ g0, const float* __restrict__ b0,
    const float* __restrict__ m0, const float* __restrict__ v0,
    const float* __restrict__ g1, const float* __restrict__ b1,
    const float* __restrict__ m1, const float* __restrict__ v1,
    const float* __restrict__ g2, const float* __restrict__ b2,
    const float* __restrict__ m2, const float* __restrict__ v2,
    const float* __restrict__ g3, const float* __restrict__ b3,
    const float* __restrict__ m3, const float* __restrict__ v3,
    u16* __restrict__ W0bf, float* __restrict__ A1, float* __restrict__ B1,
    float* __restrict__ A2, float* __restrict__ B2,
    float* __restrict__ A3, float* __restrict__ B3)
{
    __shared__ float red[256];
    const int h = blockIdx.x;
    const int c = threadIdx.x;

    float inv0 = g0[c] / sqrtf(v0[c] + 1e-5f);
    float add0 = b0[c] - m0[c] * inv0;
    float w = w_expand[h * C_DIM + c];
    W0bf[h * C_DIM + c] = f2bf(w * inv0);
    red[c] = add0 * w;
    __syncthreads();
    for (int s = 128; s > 0; s >>= 1) {
        if (c < s) red[c] += red[c + s];
        __syncthreads();
    }
    if (c == 0) {
        float bias0 = red[0];
        float inv1 = g1[h] / sqrtf(v1[h] + 1e-5f);
        A1[h] = inv1;
        B1[h] = bias0 * inv1 + (b1[h] - m1[h] * inv1);
        float inv2 = g2[h] / sqrtf(v2[h] + 1e-5f);
        A2[h] = inv2;
        B2[h] = b2[h] - m2[h] * inv2;
        if (h < C_DIM) {
            float inv3 = g3[h] / sqrtf(v3[h] + 1e-5f);
            A3[h] = inv3;
            B3[h] = b3[h] - m3[h] * inv3;
        }
    }
}

__global__ __launch_bounds__(256) void convw_kernel(
    const float* __restrict__ w, u16* __restrict__ o, int n)
{
    int i = blockIdx.x * 256 + threadIdx.x;
    if (i < n) o[i] = f2bf(w[i]);
}

// ---------------------------------------------------------------------------
// prep2: build per-(h,lane) Toeplitz A-fragments for the dw MFMA.
// T[i][k] = w[k - i - 1]  (i = lane&15, k = (lane>>4)*8 + j  [+32 for A2])
// tab[0][h][lane][8] = A1 frag, tab[1][h][lane][8] = A2 frag (bf16)
// ---------------------------------------------------------------------------
__global__ __launch_bounds__(64) void prep2_kernel(
    const float* __restrict__ w_dw, u16* __restrict__ tab)
{
    const int h = blockIdx.x;
    const int lane = threadIdx.x;
    const int l15 = lane & 15, kg = lane >> 4;
    u16* dA = tab + ((size_t)h * 64 + lane) * 8;
    u16* dB = tab + (size_t)H_DIM * 64 * 8 + ((size_t)h * 64 + lane) * 8;
#pragma unroll
    for (int j = 0; j < 8; ++j) {
        int m1 = kg * 8 + j - l15 - 1;
        int m2 = m1 + 32;
        dA[j] = (m1 >= 0 && m1 < KW) ? f2bf(w_dw[h * KW + m1]) : (u16)0;
        dB[j] = (m2 >= 0 && m2 < KW) ? f2bf(w_dw[h * KW + m2]) : (u16)0;
    }
}

// ---------------------------------------------------------------------------
// convx: x fp32 [C][L] -> xT bf16 [L][C]  (per batch, LDS tile transpose)
// ---------------------------------------------------------------------------
__global__ __launch_bounds__(256) void convx_kernel(
    const float* __restrict__ x, u16* __restrict__ xT)
{
    __shared__ u16 t_s[64][68];
    const int b = blockIdx.z, c0 = blockIdx.y * 64, l0 = blockIdx.x * 64;
    const int tid = threadIdx.x;
    const float* xb = x + (size_t)b * C_DIM * L_DIM;
    {
        const int cl = tid >> 2, lg = (tid & 3) * 16;
        const float* src = xb + (size_t)(c0 + cl) * L_DIM + l0 + lg;
#pragma unroll
        for (int j = 0; j < 16; j += 4) {
            float4 v = *(const float4*)(src + j);
            ushort4 o;
            o.x = f2bf(v.x); o.y = f2bf(v.y); o.z = f2bf(v.z); o.w = f2bf(v.w);
            *(ushort4*)&t_s[cl][lg + j] = o;
        }
    }
    __syncthreads();
    {
        const int ll = tid >> 2, cg = (tid & 3) * 16;
        u32 w0[4], w1[4];
#pragma unroll
        for (int j = 0; j < 4; ++j) {
            w0[j] = (u32)t_s[cg + 2*j][ll] | ((u32)t_s[cg + 2*j + 1][ll] << 16);
            w1[j] = (u32)t_s[cg + 8 + 2*j][ll] | ((u32)t_s[cg + 9 + 2*j][ll] << 16);
        }
        u16* dst = xT + ((size_t)b * L_DIM + l0 + ll) * C_DIM + c0 + cg;
        uint4 o0; o0.x = w0[0]; o0.y = w0[1]; o0.z = w0[2]; o0.w = w0[3];
        uint4 o1; o1.x = w1[0]; o1.y = w1[1]; o1.z = w1[2]; o1.w = w1[3];
        *(uint4*)(dst)     = o0;
        *(uint4*)(dst + 8) = o1;
    }
}

// ---------------------------------------------------------------------------
// gemm_bt: D = A[M][K] * BT[N][K]^T, bf16 MFMA 16x16x32, 128x128 tile, BK=64
// EPI 0: Out = bf16 h1, v = relu(acc*Sa[row] + Sb[row])
// EPI 1: Out = fp32 out, v = acc*Sa[row] + Sb[row] + Xs[row][col]
// ---------------------------------------------------------------------------
template<int KDIM, int EPI>
__global__ __launch_bounds__(256) void gemm_bt_kernel(
    const u16* __restrict__ A,    // [M][KDIM] bf16
    const u16* __restrict__ BT,   // per b: [L_DIM][KDIM] bf16
    void* __restrict__ Out,
    const float* __restrict__ Sa, const float* __restrict__ Sb,
    const float* __restrict__ Xs)
{
    __shared__ short Asm[128 * 64];
    __shared__ short Bsm[128 * 64];
    const int b = blockIdx.z;
    const int bm = blockIdx.y * 128;
    const int bn = blockIdx.x * 128;
    const int tid = threadIdx.x;
    const int wave = tid >> 6, lane = tid & 63;
    const int wr = wave >> 1, wc = wave & 1;
    const int l15 = lane & 15, kg = lane >> 4;

    const u16* Bb = BT + (size_t)b * L_DIM * KDIM;

    const int srow = wave * 32 + (lane >> 3);
    const int scol = (lane & 7) * 8;
    const u16* gA = A  + (size_t)(bm + srow) * KDIM + scol;
    const u16* gB = Bb + (size_t)(bn + srow) * KDIM + scol;
    short* lA = Asm + wave * 32 * 64;
    short* lB = Bsm + wave * 32 * 64;

    f32x4 acc[4][4] = {};

    for (int kt = 0; kt < KDIM / 64; ++kt) {
        __syncthreads();
#pragma unroll
        for (int j = 0; j < 4; ++j) {
            async16(lA + j * 8 * 64, gA + (size_t)j * 8 * KDIM);
            async16(lB + j * 8 * 64, gB + (size_t)j * 8 * KDIM);
        }
        gA += 64; gB += 64;
        __syncthreads();
#pragma unroll
        for (int ks = 0; ks < 2; ++ks) {
            bf16x8 af[4], bf[4];
#pragma unroll
            for (int m = 0; m < 4; ++m)
                af[m] = *(const bf16x8*)&Asm[(wr * 64 + m * 16 + l15) * 64 + ks * 32 + kg * 8];
#pragma unroll
            for (int n = 0; n < 4; ++n)
                bf[n] = *(const bf16x8*)&Bsm[(wc * 64 + n * 16 + l15) * 64 + ks * 32 + kg * 8];
#pragma unroll
            for (int m = 0; m < 4; ++m)
#pragma unroll
                for (int n = 0; n < 4; ++n)
                    acc[m][n] = __builtin_amdgcn_mfma_f32_16x16x32_bf16(
                        af[m], bf[n], acc[m][n], 0, 0, 0);
        }
    }

    const int orow0 = bm + wr * 64;
    const int ocol = bn + wc * 64 + l15;
    if constexpr (EPI == 0) {
        u16* O = (u16*)Out + (size_t)b * H_DIM * L_DIM;
#pragma unroll
        for (int m = 0; m < 4; ++m)
#pragma unroll
        for (int r = 0; r < 4; ++r) {
            const int row = orow0 + m * 16 + kg * 4 + r;
            const float s = Sa[row], t = Sb[row];
#pragma unroll
            for (int n = 0; n < 4; ++n) {
                float v = acc[m][n][r] * s + t;
                v = v > 0.f ? v : 0.f;
                O[(size_t)row * L_DIM + ocol + n * 16] = f2bf(v);
            }
        }
    } else {
        float* O = (float*)Out + (size_t)b * C_DIM * L_DIM;
        const float* X = Xs + (size_t)b * C_DIM * L_DIM;
#pragma unroll
        for (int m = 0; m < 4; ++m)
#pragma unroll
        for (int r = 0; r < 4; ++r) {
            const int row = orow0 + m * 16 + kg * 4 + r;
            const float s = Sa[row], t = Sb[row];
#pragma unroll
            for (int n = 0; n < 4; ++n) {
                float v = acc[m][n][r] * s + t + X[(size_t)row * L_DIM + ocol + n * 16];
                O[(size_t)row * L_DIM + ocol + n * 16] = v;
            }
        }
    }
}

// ---------------------------------------------------------------------------
// dw (MFMA Toeplitz): y[l] = sum_u w[u] x[l+u-15] as O = T*X per 16x16 tile.
// Block: 32 h x 256 l, 4 waves; wave owns 8 h. Per h: 2 MFMA 16x16x32.
//   A-frag (T) from precomputed tab; X-frag = aligned ds_read_b128 from in_s
//   (origin l0-16, window 320). C/D: lane has 4 consecutive l (fixed h).
// Epilogue: BN2+ReLU fp32, cvt_pk pairs 2 adjacent h -> u32, XOR-swizzled
// out_s[256][34] (c' = c ^ ((row>>4)&3)), then coalesced transposed store.
// ---------------------------------------------------------------------------
__global__ __launch_bounds__(256) void dw_kernel(
    const u16* __restrict__ h1, const u16* __restrict__ tab,
    u16* __restrict__ h2T,
    const float* __restrict__ A2, const float* __restrict__ B2)
{
    __shared__ u16 in_s[32][320];
    __shared__ u16 out_s[256][34];
    const int b = blockIdx.z, h0 = blockIdx.y * 32, l0 = blockIdx.x * 256;
    const int tid = threadIdx.x;
    const int wave = tid >> 6, lane = tid & 63;
    const int l15 = lane & 15, kg = lane >> 4;
    const u16* hb = h1 + (size_t)b * H_DIM * L_DIM;

    // stage rows h0..h0+31, window [l0-16, l0+304), zero-padded (aligned 16B)
#pragma unroll
    for (int it = 0; it < 5; ++it) {
        const int idx = tid + it * 256;
        const int r = idx / 40, g = idx % 40;
        const int bl = l0 - 16 + g * 8;
        const u16* src = hb + (size_t)(h0 + r) * L_DIM + bl;
        uint4 val;
        if (bl >= 0 && bl + 8 <= L_DIM) {
            val = *(const uint4*)src;
        } else {
            u16 t[8];
#pragma unroll
            for (int e = 0; e < 8; ++e)
                t[e] = (bl + e >= 0 && bl + e < L_DIM) ? src[e] : (u16)0;
            val.x = (u32)t[0] | ((u32)t[1] << 16);
            val.y = (u32)t[2] | ((u32)t[3] << 16);
            val.z = (u32)t[4] | ((u32)t[5] << 16);
            val.w = (u32)t[6] | ((u32)t[7] << 16);
        }
        *(uint4*)&in_s[r][g * 8] = val;
    }
    __syncthreads();

    const u16* tabB = tab + (size_t)H_DIM * 64 * 8;
    const int xoff = 16 * l15 + 8 * kg;
#pragma unroll
    for (int hp = 0; hp < 4; ++hp) {
        const int hlA = wave * 8 + hp * 2;      // even local h
        const int hA = h0 + hlA, hB = hA + 1;
        bf16x8 a1A = *(const bf16x8*)(tab  + ((size_t)hA * 64 + lane) * 8);
        bf16x8 a2A = *(const bf16x8*)(tabB + ((size_t)hA * 64 + lane) * 8);
        bf16x8 a1B = *(const bf16x8*)(tab  + ((size_t)hB * 64 + lane) * 8);
        bf16x8 a2B = *(const bf16x8*)(tabB + ((size_t)hB * 64 + lane) * 8);
        bf16x8 x1A = *(const bf16x8*)&in_s[hlA][xoff];
        bf16x8 x2A = *(const bf16x8*)&in_s[hlA][xoff + 32];
        bf16x8 x1B = *(const bf16x8*)&in_s[hlA + 1][xoff];
        bf16x8 x2B = *(const bf16x8*)&in_s[hlA + 1][xoff + 32];
        f32x4 accA = {}, accB = {};
        accA = __builtin_amdgcn_mfma_f32_16x16x32_bf16(a1A, x1A, accA, 0, 0, 0);
        accA = __builtin_amdgcn_mfma_f32_16x16x32_bf16(a2A, x2A, accA, 0, 0, 0);
        accB = __builtin_amdgcn_mfma_f32_16x16x32_bf16(a1B, x1B, accB, 0, 0, 0);
        accB = __builtin_amdgcn_mfma_f32_16x16x32_bf16(a2B, x2B, accB, 0, 0, 0);
        const float sA = A2[hA], tA = B2[hA];
        const float sB = A2[hB], tB = B2[hB];
        const int c = wave * 4 + hp;
        const int lbase = 16 * l15 + 4 * kg;
#pragma unroll
        for (int r = 0; r < 4; ++r) {
            float vA = accA[r] * sA + tA; vA = vA > 0.f ? vA : 0.f;
            float vB = accB[r] * sB + tB; vB = vB > 0.f ? vB : 0.f;
            u32 pk;
            asm("v_cvt_pk_bf16_f32 %0, %1, %2" : "=v"(pk) : "v"(vA), "v"(vB));
            const int X = lbase + r;
            const int cp = c ^ ((X >> 4) & 3);
            *(u32*)&out_s[X][cp * 2] = pk;
        }
    }
    __syncthreads();

    // coalesced transposed store: thread = one l-row, 64 B (h0..h0+31)
    u32 vals[16];
#pragma unroll
    for (int c = 0; c < 16; ++c) {
        const int cp = c ^ ((tid >> 4) & 3);
        vals[c] = *(const u32*)&out_s[tid][cp * 2];
    }
    u16* dst = h2T + ((size_t)b * L_DIM + l0 + tid) * H_DIM + h0;
#pragma unroll
    for (int q = 0; q < 4; ++q) {
        uint4 o;
        o.x = vals[q * 4 + 0]; o.y = vals[q * 4 + 1];
        o.z = vals[q * 4 + 2]; o.w = vals[q * 4 + 3];
        ((uint4*)dst)[q] = o;
    }
}

extern "C" void kernel_launch(void* const* d_in, const int* in_sizes, int n_in,
                              void* d_out, int out_size, void* d_ws, size_t ws_size,
                              hipStream_t stream) {
    const float* x        = (const float*)d_in[0];
    const float* w_expand = (const float*)d_in[1];
    const float* w_dw     = (const float*)d_in[2];
    const float* w_proj   = (const float*)d_in[3];
    const float* g0 = (const float*)d_in[4],  *b0 = (const float*)d_in[5];
    const float* m0 = (const float*)d_in[6],  *v0 = (const float*)d_in[7];
    const float* g1 = (const float*)d_in[8],  *b1 = (const float*)d_in[9];
    const float* m1 = (const float*)d_in[10], *v1 = (const float*)d_in[11];
    const float* g2 = (const float*)d_in[12], *b2 = (const float*)d_in[13];
    const float* m2 = (const float*)d_in[14], *v2 = (const float*)d_in[15];
    const float* g3 = (const float*)d_in[16], *b3 = (const float*)d_in[17];
    const float* m3 = (const float*)d_in[18], *v3 = (const float*)d_in[19];
    float* out = (float*)d_out;

    const int B = in_sizes[0] / (C_DIM * L_DIM);

    char* base = (char*)d_ws;
    size_t off = 0;
    u16* W0bf = (u16*)(base + off); off += (size_t)H_DIM * C_DIM * 2;
    u16* Wpbf = (u16*)(base + off); off += (size_t)C_DIM * H_DIM * 2;
    u16* tab  = (u16*)(base + off); off += (size_t)2 * H_DIM * 64 * 8 * 2;
    float* A1p = (float*)(base + off); off += H_DIM * 4;
    float* B1p = (float*)(base + off); off += H_DIM * 4;
    float* A2p = (float*)(base + off); off += H_DIM * 4;
    float* B2p = (float*)(base + off); off += H_DIM * 4;
    float* A3p = (float*)(base + off); off += C_DIM * 4;
    float* B3p = (float*)(base + off); off += C_DIM * 4;
    off = (off + 255) & ~(size_t)255;

    const size_t per_b = ((size_t)L_DIM * C_DIM + 2 * (size_t)H_DIM * L_DIM) * 2;
    int nb = 1;
    const int cands[6] = {32, 16, 8, 4, 2, 1};
    for (int i = 0; i < 6; ++i) {
        if (B % cands[i]) continue;
        if (off + per_b * cands[i] <= ws_size) { nb = cands[i]; break; }
    }
    u16* xT  = (u16*)(base + off);
    u16* h1  = xT + (size_t)nb * L_DIM * C_DIM;
    u16* h2T = h1 + (size_t)nb * H_DIM * L_DIM;

    prep_kernel<<<H_DIM, 256, 0, stream>>>(
        w_expand, g0, b0, m0, v0, g1, b1, m1, v1, g2, b2, m2, v2,
        g3, b3, m3, v3, W0bf, A1p, B1p, A2p, B2p, A3p, B3p);
    convw_kernel<<<(C_DIM * H_DIM + 255) / 256, 256, 0, stream>>>(
        w_proj, Wpbf, C_DIM * H_DIM);
    prep2_kernel<<<H_DIM, 64, 0, stream>>>(w_dw, tab);

    for (int cs = 0; cs < B; cs += nb) {
        const float* xb = x + (size_t)cs * C_DIM * L_DIM;
        float* ob = out + (size_t)cs * C_DIM * L_DIM;
        convx_kernel<<<dim3(L_DIM / 64, C_DIM / 64, nb), 256, 0, stream>>>(xb, xT);
        gemm_bt_kernel<C_DIM, 0><<<dim3(L_DIM / 128, H_DIM / 128, nb), 256, 0, stream>>>(
            W0bf, xT, h1, A1p, B1p, nullptr);
        dw_kernel<<<dim3(L_DIM / 256, H_DIM / 32, nb), 256, 0, stream>>>(
            h1, tab, h2T, A2p, B2p);
        gemm_bt_kernel<H_DIM, 1><<<dim3(L_DIM / 128, C_DIM / 128, nb), 256, 0, stream>>>(
            Wpbf, h2T, ob, A3p, B3p, xb);
    }
}